// Round 4
// baseline (1616.022 us; speedup 1.0000x reference)
//
#include <hip/hip_runtime.h>

#define NB 524288
#define ND 64
#define NH 19
#define NP 10      // padded pair count (20 elems)
#define NBLK 2048  // blocks for ltc_absum and ltc_fused (256 threads each)

typedef float v2f __attribute__((ext_vector_type(2)));

__device__ __forceinline__ v2f splat2(float x) { return (v2f){x, x}; }
__device__ __forceinline__ v2f fma2(v2f a, v2f b, v2f c) {
    return __builtin_elementwise_fma(a, b, c);
}
__device__ __forceinline__ float rfl(float v) {  // readfirstlane (force SGPR)
    union { float f; int i; } a; a.f = v;
    a.i = __builtin_amdgcn_readfirstlane(a.i);
    return a.f;
}

// Padé(5,4) tanh, clamped: max |err| ~1e-3 (at x~3.5), well under tolerance.
__device__ __forceinline__ v2f tanh2(v2f x) {
    v2f x2 = x * x;
    v2f n  = fma2(x2, x2 + splat2(105.f), splat2(945.f));
    v2f d  = fma2(x2, fma2(x2, splat2(15.f), splat2(420.f)), splat2(945.f));
    v2f xn = x * n;
    v2f y  = {xn.x * __builtin_amdgcn_rcpf(d.x), xn.y * __builtin_amdgcn_rcpf(d.y)};
    y = __builtin_elementwise_min(y, splat2(1.f));
    y = __builtin_elementwise_max(y, splat2(-1.f));
    return y;
}

// Setup: pair-transposed weight tables so packed FMAs get contiguous uniform
// float2 loads. W?2[k][t] = (W[2t][k], W[2t+1][k]), pad t=9.y with 0.
extern "C" __global__ void __launch_bounds__(64)
ltc_setup(const float* __restrict__ Wi, const float* __restrict__ bi,
          const float* __restrict__ Wr, const float* __restrict__ Wo,
          const float* __restrict__ bo,
          float2* __restrict__ Wi2, float2* __restrict__ bi2,
          float2* __restrict__ Wr2, float2* __restrict__ Wo2,
          float2* __restrict__ bo2)
{
    for (int i = threadIdx.x; i < NH * NP; i += 64) {
        int k = i / NP, t = i % NP;
        float rx = Wr[(2 * t) * NH + k];
        float ry = (2 * t + 1 < NH) ? Wr[(2 * t + 1) * NH + k] : 0.f;
        Wr2[i] = make_float2(rx, ry);
        float ox = Wo[(2 * t) * NH + k];
        float oy = (2 * t + 1 < NH) ? Wo[(2 * t + 1) * NH + k] : 0.f;
        Wo2[i] = make_float2(ox, oy);
    }
    // Wi2[col*NP + t] = (Wi[2t][col], Wi[2t+1][col]), col = 0..63
    for (int i = threadIdx.x; i < ND * NP; i += 64) {
        int col = i / NP, t = i % NP;
        float ax = Wi[(2 * t) * ND + col];
        float ay = (2 * t + 1 < NH) ? Wi[(2 * t + 1) * ND + col] : 0.f;
        Wi2[i] = make_float2(ax, ay);
    }
    if (threadIdx.x < NP) {
        int t = threadIdx.x;
        bo2[t] = make_float2(bo[2 * t], (2 * t + 1 < NH) ? bo[2 * t + 1] : 0.f);
        bi2[t] = make_float2(bi[2 * t], (2 * t + 1 < NH) ? bi[2 * t + 1] : 0.f);
    }
}

// Kernel 1: pure |x| reduction (also warms L3 with x). 134 MB read, ~22 us.
extern "C" __global__ void __launch_bounds__(256)
ltc_absum(const float* __restrict__ x, float* __restrict__ partials)
{
    __shared__ float red[4];
    const int t = threadIdx.x;
    const float4* xg = (const float4*)x + (size_t)blockIdx.x * 4096;
    float s = 0.f;
#pragma unroll
    for (int i = 0; i < 16; ++i) {
        const float4 v = xg[i * 256 + t];
        s += fabsf(v.x) + fabsf(v.y) + fabsf(v.z) + fabsf(v.w);
    }
#pragma unroll
    for (int off = 32; off > 0; off >>= 1) s += __shfl_down(s, off, 64);
    if ((t & 63) == 0) red[t >> 6] = s;
    __syncthreads();
    if (t == 0) partials[blockIdx.x] = red[0] + red[1] + red[2] + red[3];
}

// Kernel 2: fused matvec + recurrence + output.
// r1 vs r3 showed identical VALU-busy work at 52 vs 88 VGPR -> no AGPR
// shuttling ever existed; the kernel is issue-efficient (~15k cyc/wave ideal,
// matching per-SIMD issue) but LATENCY-stalled on the 190-per-step weight
// reloads (load->fma chains, ~120cy each, only 40cy of FMA cover).
// Fixes this round:
//   - all weight tables staged to LDS once per block (uniform ds_read bcast)
//   - k-loop weight rows explicitly double-buffered in registers: row k+1
//     prefetched during row k's FMAs; row 0 of the next step prefetched
//     under tanh+update (~200cy of cover)
//   - LDS 43.1KB -> 3 blocks/CU -> allocator budget 170 regs: state (~95) +
//     prefetch buffers (40) fit without spills
extern "C" __global__ void __launch_bounds__(256)
ltc_fused(const float* __restrict__ x, const float* __restrict__ partials,
          const v2f* __restrict__ Wi2, const v2f* __restrict__ bi2,
          const v2f* __restrict__ Wr2, const v2f* __restrict__ Wo2,
          const v2f* __restrict__ bo2, const float* __restrict__ tau,
          const float* __restrict__ ta, const int* __restrict__ steps_p,
          float* __restrict__ out)
{
    __shared__ float lds[4 * 64 * 34];  // phase-B tiles; reused for staging
    __shared__ v2f wlds[1040];          // Wi2 640 | Wr2 190 | Wo2 190 | bi 10 | bo 10
    __shared__ float red[4];
    const int t = threadIdx.x;
    const int l = t & 63, w = t >> 6;
    const int rowbase = blockIdx.x * 256;

    // --- stage weight tables into LDS (completes at the urgency barrier) ---
#pragma unroll
    for (int i = 0; i < 3; ++i) {
        int idx = t + 256 * i;
        if (idx < 640) wlds[idx] = Wi2[idx];
    }
    if (t < 190) {
        wlds[640 + t] = Wr2[t];
        wlds[830 + t] = Wo2[t];
    }
    if (t < NP) {
        wlds[1020 + t] = bi2[t];
        wlds[1030 + t] = bo2[t];
    }
    const v2f* wi_l = &wlds[0];
    const v2f* wr_l = &wlds[640];
    const v2f* wo_l = &wlds[830];

    // --- urgency: deterministic re-reduction of the 2048 partials ---
    float ps = 0.f;
#pragma unroll
    for (int i = 0; i < NBLK / 256; ++i) ps += partials[t + 256 * i];
#pragma unroll
    for (int off = 32; off > 0; off >>= 1) ps += __shfl_down(ps, off, 64);
    if ((t & 63) == 0) red[t >> 6] = ps;
    __syncthreads();  // also covers weight staging
    const float total = red[0] + red[1] + red[2] + red[3];
    const float u = rfl(fmaxf(total * (1.f / ((float)NB * (float)ND)), 0.01f));
    const float inv_u = 1.f / u;

    // --- phase B: m2 = x @ Wi^T + bi (packed; Wi from LDS) ---
    v2f m2[NP];
#pragma unroll
    for (int j = 0; j < NP; ++j) m2[j] = wlds[1020 + j];  // bi2
    {
        float* tw = lds + w * (64 * 34);
        const float4* xg = (const float4*)x + (size_t)(rowbase + w * 64) * 16;
#pragma unroll
        for (int c = 0; c < 2; ++c) {
#pragma unroll
            for (int i = 0; i < 8; ++i) {
                const int flat = i * 64 + l, row = flat >> 3, cq = flat & 7;
                const float4 v = xg[row * 16 + c * 8 + cq];
                *(float2*)&tw[row * 34 + cq * 4]     = make_float2(v.x, v.y);
                *(float2*)&tw[row * 34 + cq * 4 + 2] = make_float2(v.z, v.w);
            }
            __syncthreads();  // guards tile write->read ordering
#pragma unroll
            for (int q = 0; q < 16; ++q) {
                const float2 v = *(const float2*)&tw[l * 34 + 2 * q];
                const int col = c * 32 + 2 * q;
                const v2f vx = splat2(v.x), vy = splat2(v.y);
                const v2f* wc0 = wi_l + col * NP;
                const v2f* wc1 = wi_l + (col + 1) * NP;
#pragma unroll
                for (int j = 0; j < NP; ++j) m2[j] = fma2(vx, wc0[j], m2[j]);
#pragma unroll
                for (int j = 0; j < NP; ++j) m2[j] = fma2(vy, wc1[j], m2[j]);
            }
            __syncthreads();  // reads done before next chunk overwrites tile
        }
    }

    // --- rr2 ---
    v2f rr2[NP];
#pragma unroll
    for (int j = 0; j < NP; ++j) {
        int j0 = 2 * j, j1 = (2 * j + 1 < NH) ? 2 * j + 1 : 2 * j;
        float t0 = fminf(10.f, fmaxf(0.01f, tau[j0] * (1.f - ta[j0]) + ta[j0] * inv_u));
        float t1 = fminf(10.f, fmaxf(0.01f, tau[j1] * (1.f - ta[j1]) + ta[j1] * inv_u));
        rr2[j] = (v2f){0.01f / t0, 0.01f / t1};
    }

    v2f h2[NP];
#pragma unroll
    for (int j = 0; j < NP; ++j) h2[j] = splat2(0.f);

    // --- recurrence with double-buffered weight-row prefetch ---
    // row k lives in (k&1) ? wB : wA; row k+1 is loaded during row k's FMAs;
    // row 0 for the NEXT step is reloaded under tanh/update.
    const int steps = *steps_p;
    v2f wA[NP], wB[NP];
#pragma unroll
    for (int j = 0; j < NP; ++j) wA[j] = wr_l[j];  // row 0
#pragma unroll 1
    for (int s = 0; s < steps; ++s) {
        v2f p2[NP];
        {   // k = 0: uses wA, prefetch row 1 -> wB
            const v2f hb = splat2(h2[0].x);
#pragma unroll
            for (int j = 0; j < NP; ++j) wB[j] = wr_l[NP + j];
#pragma unroll
            for (int j = 0; j < NP; ++j) p2[j] = fma2(hb, wA[j], m2[j]);
        }
#pragma unroll
        for (int k = 1; k < NH; ++k) {
            const float hk = (k & 1) ? h2[k >> 1].y : h2[k >> 1].x;
            const v2f hb = splat2(hk);
            if (k < NH - 1) {  // prefetch row k+1 into the non-current buffer
                if (k & 1) {
#pragma unroll
                    for (int j = 0; j < NP; ++j) wA[j] = wr_l[(k + 1) * NP + j];
                } else {
#pragma unroll
                    for (int j = 0; j < NP; ++j) wB[j] = wr_l[(k + 1) * NP + j];
                }
            }
            if (k & 1) {
#pragma unroll
                for (int j = 0; j < NP; ++j) p2[j] = fma2(hb, wB[j], p2[j]);
            } else {
#pragma unroll
                for (int j = 0; j < NP; ++j) p2[j] = fma2(hb, wA[j], p2[j]);
            }
        }
        // reload row 0 for next step; hides under tanh + h-update
#pragma unroll
        for (int j = 0; j < NP; ++j) wA[j] = wr_l[j];
#pragma unroll
        for (int j = 0; j < NP; ++j) p2[j] = tanh2(p2[j]);  // reuse p2 as act
#pragma unroll
        for (int j = 0; j < NP; ++j) h2[j] = fma2(rr2[j], p2[j] - h2[j], h2[j]);
    }

    // --- epilogue: o = h @ Wo^T + bo (Wo from LDS), stage, float4 stores ---
    v2f o2[NP];
    {
        const v2f hb = splat2(h2[0].x);
#pragma unroll
        for (int j = 0; j < NP; ++j) o2[j] = fma2(hb, wo_l[j], wlds[1030 + j]);
    }
#pragma unroll
    for (int k = 1; k < NH; ++k) {
        const float hk = (k & 1) ? h2[k >> 1].y : h2[k >> 1].x;
        const v2f hb = splat2(hk);
        const v2f* worow = wo_l + k * NP;
#pragma unroll
        for (int j = 0; j < NP; ++j) o2[j] = fma2(hb, worow[j], o2[j]);
    }
    float* st = lds;  // reuse tile LDS: [256][19] staging (19456 B)
    __syncthreads();
#pragma unroll
    for (int j = 0; j < NH; ++j)
        st[t * NH + j] = (j & 1) ? o2[j >> 1].y : o2[j >> 1].x;
    __syncthreads();
    {
        const float4* s4 = (const float4*)st;
        float4* o4 = (float4*)(out + (size_t)blockIdx.x * 256 * NH);
#pragma unroll
        for (int i = 0; i < 4; ++i) o4[t + i * 256] = s4[t + i * 256];
        if (t + 1024 < 1216) o4[t + 1024] = s4[t + 1024];
    }
    __syncthreads();
#pragma unroll
    for (int j = 0; j < NH; ++j)
        st[t * NH + j] = (j & 1) ? h2[j >> 1].y : h2[j >> 1].x;
    __syncthreads();
    {
        const float4* s4 = (const float4*)st;
        float4* o4 = (float4*)(out + (size_t)NB * NH + (size_t)blockIdx.x * 256 * NH);
#pragma unroll
        for (int i = 0; i < 4; ++i) o4[t + i * 256] = s4[t + i * 256];
        if (t + 1024 < 1216) o4[t + 1024] = s4[t + 1024];
    }
}

extern "C" void kernel_launch(void* const* d_in, const int* in_sizes, int n_in,
                              void* d_out, int out_size, void* d_ws, size_t ws_size,
                              hipStream_t stream)
{
    const float* x   = (const float*)d_in[0];
    const float* Wi  = (const float*)d_in[1];
    const float* bi  = (const float*)d_in[2];
    const float* Wr  = (const float*)d_in[3];
    const float* Wo  = (const float*)d_in[4];
    const float* bo  = (const float*)d_in[5];
    const float* tau = (const float*)d_in[6];
    const float* ta  = (const float*)d_in[7];
    const int* steps = (const int*)d_in[8];
    float* out = (float*)d_out;

    // ws layout (all fully overwritten every call)
    float*  partials = (float*)d_ws;                    // 8192 B
    float2* Wr2 = (float2*)((char*)d_ws + 8192);        // 1520 B
    float2* Wo2 = (float2*)((char*)d_ws + 9728);        // 1520 B
    float2* bo2 = (float2*)((char*)d_ws + 11264);       // 80 B
    float2* bi2 = (float2*)((char*)d_ws + 11360);       // 80 B
    float2* Wi2 = (float2*)((char*)d_ws + 11456);       // 5120 B

    ltc_setup<<<1, 64, 0, stream>>>(Wi, bi, Wr, Wo, bo, Wi2, bi2, Wr2, Wo2, bo2);
    ltc_absum<<<NBLK, 256, 0, stream>>>(x, partials);
    ltc_fused<<<NBLK, 256, 0, stream>>>(x, partials, (const v2f*)Wi2,
                                        (const v2f*)bi2, (const v2f*)Wr2,
                                        (const v2f*)Wo2, (const v2f*)bo2,
                                        tau, ta, steps, out);
}

// Round 5
// 406.317 us; speedup vs baseline: 3.9772x; 3.9772x over previous
//
#include <hip/hip_runtime.h>

#define NB 524288
#define ND 64
#define NH 19
#define NP 10      // padded pair count (20 elems)
#define NBLK 2048  // blocks for ltc_absum and ltc_fused (256 threads each)

typedef float v2f __attribute__((ext_vector_type(2)));

__device__ __forceinline__ v2f splat2(float x) { return (v2f){x, x}; }
__device__ __forceinline__ v2f fma2(v2f a, v2f b, v2f c) {
    return __builtin_elementwise_fma(a, b, c);
}
__device__ __forceinline__ float rfl(float v) {  // readfirstlane (force SGPR)
    union { float f; int i; } a; a.f = v;
    a.i = __builtin_amdgcn_readfirstlane(a.i);
    return a.f;
}

// exp2-based tanh: tanh(x) = 1 - 2/(1 + 2^(2*log2e*x)). 7 ops/pair (vs 12
// for the old Pade) and ~1e-6 accurate. Saturation: exp2->inf gives rcp->0
// -> +1; exp2->0 gives rcp(1)=1 -> -1. No clamp needed.
__device__ __forceinline__ v2f tanh2(v2f x) {
    const float c = 2.8853900817779268f;  // 2*log2(e)
    float ex = __builtin_amdgcn_exp2f(x.x * c);
    float ey = __builtin_amdgcn_exp2f(x.y * c);
    v2f r = {__builtin_amdgcn_rcpf(ex + 1.f), __builtin_amdgcn_rcpf(ey + 1.f)};
    return fma2(splat2(-2.f), r, splat2(1.f));
}

// Per-wave LDS fence: each wave only touches its own tile region in phase B,
// so a block barrier is over-sync. lgkmcnt(0) orders this wave's ds ops;
// sched_barrier stops the compiler hoisting consumers above it (rule #18).
#define WAVE_LDS_FENCE()                                      \
    do {                                                      \
        asm volatile("s_waitcnt lgkmcnt(0)" ::: "memory");    \
        __builtin_amdgcn_sched_barrier(0);                    \
    } while (0)

// Setup: pair-transposed weight tables so packed FMAs get contiguous uniform
// float2 loads. W?2[k][t] = (W[2t][k], W[2t+1][k]), pad t=9.y with 0.
extern "C" __global__ void __launch_bounds__(64)
ltc_setup(const float* __restrict__ Wi, const float* __restrict__ bi,
          const float* __restrict__ Wr, const float* __restrict__ Wo,
          const float* __restrict__ bo,
          float2* __restrict__ Wi2, float2* __restrict__ bi2,
          float2* __restrict__ Wr2, float2* __restrict__ Wo2,
          float2* __restrict__ bo2)
{
    for (int i = threadIdx.x; i < NH * NP; i += 64) {
        int k = i / NP, t = i % NP;
        float rx = Wr[(2 * t) * NH + k];
        float ry = (2 * t + 1 < NH) ? Wr[(2 * t + 1) * NH + k] : 0.f;
        Wr2[i] = make_float2(rx, ry);
        float ox = Wo[(2 * t) * NH + k];
        float oy = (2 * t + 1 < NH) ? Wo[(2 * t + 1) * NH + k] : 0.f;
        Wo2[i] = make_float2(ox, oy);
    }
    // Wi2[col*NP + t] = (Wi[2t][col], Wi[2t+1][col]), col = 0..63
    for (int i = threadIdx.x; i < ND * NP; i += 64) {
        int col = i / NP, t = i % NP;
        float ax = Wi[(2 * t) * ND + col];
        float ay = (2 * t + 1 < NH) ? Wi[(2 * t + 1) * ND + col] : 0.f;
        Wi2[i] = make_float2(ax, ay);
    }
    if (threadIdx.x < NP) {
        int t = threadIdx.x;
        bo2[t] = make_float2(bo[2 * t], (2 * t + 1 < NH) ? bo[2 * t + 1] : 0.f);
        bi2[t] = make_float2(bi[2 * t], (2 * t + 1 < NH) ? bi[2 * t + 1] : 0.f);
    }
}

// Kernel 1: pure |x| reduction (also warms L3 with x). 134 MB read.
extern "C" __global__ void __launch_bounds__(256)
ltc_absum(const float* __restrict__ x, float* __restrict__ partials)
{
    __shared__ float red[4];
    const int t = threadIdx.x;
    const float4* xg = (const float4*)x + (size_t)blockIdx.x * 4096;
    float s = 0.f;
#pragma unroll
    for (int i = 0; i < 16; ++i) {
        const float4 v = xg[i * 256 + t];
        s += fabsf(v.x) + fabsf(v.y) + fabsf(v.z) + fabsf(v.w);
    }
#pragma unroll
    for (int off = 32; off > 0; off >>= 1) s += __shfl_down(s, off, 64);
    if ((t & 63) == 0) red[t >> 6] = s;
    __syncthreads();
    if (t == 0) partials[blockIdx.x] = red[0] + red[1] + red[2] + red[3];
}

// Kernel 2: fused matvec + recurrence + output. Base = r1 (best measured
// structure: 52 VGPR + cold state in AGPR, 4 blk/CU). r4's register
// double-buffer spilled to scratch (VGPR 256, 2.8 GB spill traffic) - gone.
// This round: (1) Wr staged in LDS so the 1900 per-wave weight fetches in
// the steps loop are short-latency ds_read broadcasts, not VMEM; (2) exp2
// tanh (-500 instr/wave); (3) per-wave fences instead of block barriers in
// phase B (tiles are wave-private).
extern "C" __global__ void __launch_bounds__(256)
ltc_fused(const float* __restrict__ x, const float* __restrict__ partials,
          const v2f* __restrict__ Wi2, const v2f* __restrict__ bi2,
          const v2f* __restrict__ Wr2, const v2f* __restrict__ Wo2,
          const v2f* __restrict__ bo2, const float* __restrict__ tau,
          const float* __restrict__ ta, const int* __restrict__ steps_p,
          float* __restrict__ out)
{
    __shared__ float lds[4 * 64 * 34];  // phase-B tiles; reused for staging
    __shared__ v2f wrl[NH * NP];        // Wr2 in LDS (1520 B)
    __shared__ float red[4];
    const int t = threadIdx.x;
    const int l = t & 63, w = t >> 6;
    const int rowbase = blockIdx.x * 256;

    // --- stage Wr into LDS (completes at the urgency barrier) ---
    if (t < NH * NP) wrl[t] = Wr2[t];

    // --- urgency: deterministic re-reduction of the 2048 partials ---
    float ps = 0.f;
#pragma unroll
    for (int i = 0; i < NBLK / 256; ++i) ps += partials[t + 256 * i];
#pragma unroll
    for (int off = 32; off > 0; off >>= 1) ps += __shfl_down(ps, off, 64);
    if ((t & 63) == 0) red[t >> 6] = ps;
    __syncthreads();  // covers red[] and wrl[] staging
    const float total = red[0] + red[1] + red[2] + red[3];
    const float u = rfl(fmaxf(total * (1.f / ((float)NB * (float)ND)), 0.01f));
    const float inv_u = 1.f / u;

    // --- phase B: m2 = x @ Wi^T + bi, packed. Per-wave LDS transpose in two
    // 32-col chunks; per-wave fences only (tile is wave-private).
    v2f m2[NP];
#pragma unroll
    for (int j = 0; j < NP; ++j) m2[j] = bi2[j];
    {
        float* tw = lds + w * (64 * 34);
        const float4* xg = (const float4*)x + (size_t)(rowbase + w * 64) * 16;
#pragma unroll
        for (int c = 0; c < 2; ++c) {
#pragma unroll
            for (int i = 0; i < 8; ++i) {
                const int flat = i * 64 + l, row = flat >> 3, cq = flat & 7;
                const float4 v = xg[row * 16 + c * 8 + cq];
                *(float2*)&tw[row * 34 + cq * 4]     = make_float2(v.x, v.y);
                *(float2*)&tw[row * 34 + cq * 4 + 2] = make_float2(v.z, v.w);
            }
            WAVE_LDS_FENCE();  // this wave's tile writes -> reads
#pragma unroll
            for (int q = 0; q < 16; ++q) {
                const float2 v = *(const float2*)&tw[l * 34 + 2 * q];
                const int col = c * 32 + 2 * q;
                const v2f vx = splat2(v.x), vy = splat2(v.y);
                const v2f* wc0 = Wi2 + (size_t)col * NP;
                const v2f* wc1 = Wi2 + (size_t)(col + 1) * NP;
#pragma unroll
                for (int j = 0; j < NP; ++j) m2[j] = fma2(vx, wc0[j], m2[j]);
#pragma unroll
                for (int j = 0; j < NP; ++j) m2[j] = fma2(vy, wc1[j], m2[j]);
            }
            WAVE_LDS_FENCE();  // reads land before next chunk overwrites
        }
    }

    // --- rr2 ---
    v2f rr2[NP];
#pragma unroll
    for (int j = 0; j < NP; ++j) {
        int j0 = 2 * j, j1 = (2 * j + 1 < NH) ? 2 * j + 1 : 2 * j;
        float t0 = fminf(10.f, fmaxf(0.01f, tau[j0] * (1.f - ta[j0]) + ta[j0] * inv_u));
        float t1 = fminf(10.f, fmaxf(0.01f, tau[j1] * (1.f - ta[j1]) + ta[j1] * inv_u));
        rr2[j] = (v2f){0.01f / t0, 0.01f / t1};
    }

    v2f h2[NP];
#pragma unroll
    for (int j = 0; j < NP; ++j) h2[j] = splat2(0.f);

    // --- recurrence: h <- h + (dt/tau)*(tanh(m + h@Wr^T) - h), Wr from LDS ---
    const int steps = *steps_p;
    const v2f* wr = wrl;
    for (int s = 0; s < steps; ++s) {
        v2f p2[NP];
        {
            const v2f hb = splat2(h2[0].x);
#pragma unroll
            for (int j = 0; j < NP; ++j) p2[j] = fma2(hb, wr[j], m2[j]);
        }
#pragma unroll
        for (int k = 1; k < NH; ++k) {
            const float hk = (k & 1) ? h2[k >> 1].y : h2[k >> 1].x;
            const v2f hb = splat2(hk);
            const v2f* wrow = wr + k * NP;
#pragma unroll
            for (int j = 0; j < NP; ++j) p2[j] = fma2(hb, wrow[j], p2[j]);
        }
#pragma unroll
        for (int j = 0; j < NP; ++j) p2[j] = tanh2(p2[j]);  // reuse p2 as act
#pragma unroll
        for (int j = 0; j < NP; ++j) h2[j] = fma2(rr2[j], p2[j] - h2[j], h2[j]);
    }

    // --- epilogue: o = h @ Wo^T + bo, stage via LDS, float4 stores ---
    const v2f* wo = Wo2;
    v2f o2[NP];
    {
        const v2f hb = splat2(h2[0].x);
#pragma unroll
        for (int j = 0; j < NP; ++j) o2[j] = fma2(hb, wo[j], bo2[j]);
    }
#pragma unroll
    for (int k = 1; k < NH; ++k) {
        const float hk = (k & 1) ? h2[k >> 1].y : h2[k >> 1].x;
        const v2f hb = splat2(hk);
        const v2f* worow = wo + k * NP;
#pragma unroll
        for (int j = 0; j < NP; ++j) o2[j] = fma2(hb, worow[j], o2[j]);
    }
    float* st = lds;  // reuse tile LDS: [256][19] staging (19456 B)
    __syncthreads();  // block-wide: st overlaps other waves' tiles
#pragma unroll
    for (int j = 0; j < NH; ++j)
        st[t * NH + j] = (j & 1) ? o2[j >> 1].y : o2[j >> 1].x;
    __syncthreads();
    {
        const float4* s4 = (const float4*)st;
        float4* o4 = (float4*)(out + (size_t)blockIdx.x * 256 * NH);
#pragma unroll
        for (int i = 0; i < 4; ++i) o4[t + i * 256] = s4[t + i * 256];
        if (t + 1024 < 1216) o4[t + 1024] = s4[t + 1024];
    }
    __syncthreads();
#pragma unroll
    for (int j = 0; j < NH; ++j)
        st[t * NH + j] = (j & 1) ? h2[j >> 1].y : h2[j >> 1].x;
    __syncthreads();
    {
        const float4* s4 = (const float4*)st;
        float4* o4 = (float4*)(out + (size_t)NB * NH + (size_t)blockIdx.x * 256 * NH);
#pragma unroll
        for (int i = 0; i < 4; ++i) o4[t + i * 256] = s4[t + i * 256];
        if (t + 1024 < 1216) o4[t + 1024] = s4[t + 1024];
    }
}

extern "C" void kernel_launch(void* const* d_in, const int* in_sizes, int n_in,
                              void* d_out, int out_size, void* d_ws, size_t ws_size,
                              hipStream_t stream)
{
    const float* x   = (const float*)d_in[0];
    const float* Wi  = (const float*)d_in[1];
    const float* bi  = (const float*)d_in[2];
    const float* Wr  = (const float*)d_in[3];
    const float* Wo  = (const float*)d_in[4];
    const float* bo  = (const float*)d_in[5];
    const float* tau = (const float*)d_in[6];
    const float* ta  = (const float*)d_in[7];
    const int* steps = (const int*)d_in[8];
    float* out = (float*)d_out;

    // ws layout (all fully overwritten every call)
    float*  partials = (float*)d_ws;                    // 8192 B
    float2* Wr2 = (float2*)((char*)d_ws + 8192);        // 1520 B
    float2* Wo2 = (float2*)((char*)d_ws + 9728);        // 1520 B
    float2* bo2 = (float2*)((char*)d_ws + 11264);       // 80 B
    float2* bi2 = (float2*)((char*)d_ws + 11360);       // 80 B
    float2* Wi2 = (float2*)((char*)d_ws + 11456);       // 5120 B

    ltc_setup<<<1, 64, 0, stream>>>(Wi, bi, Wr, Wo, bo, Wi2, bi2, Wr2, Wo2, bo2);
    ltc_absum<<<NBLK, 256, 0, stream>>>(x, partials);
    ltc_fused<<<NBLK, 256, 0, stream>>>(x, partials, (const v2f*)Wi2,
                                        (const v2f*)bi2, (const v2f*)Wr2,
                                        (const v2f*)Wo2, (const v2f*)bo2,
                                        tau, ta, steps, out);
}

// Round 6
// 370.304 us; speedup vs baseline: 4.3640x; 1.0973x over previous
//
#include <hip/hip_runtime.h>

#define NB 524288
#define ND 64
#define NH 19
#define NP 10        // padded pair count (20 elems)
#define NBLK_ABS 2048  // absum blocks
#define NBLK_F 1024    // fused blocks (256 threads, 512 rows each)

typedef float v2f __attribute__((ext_vector_type(2)));

__device__ __forceinline__ v2f splat2(float x) { return (v2f){x, x}; }
__device__ __forceinline__ v2f fma2(v2f a, v2f b, v2f c) {
    return __builtin_elementwise_fma(a, b, c);
}
__device__ __forceinline__ float rfl(float v) {  // readfirstlane (force SGPR)
    union { float f; int i; } a; a.f = v;
    a.i = __builtin_amdgcn_readfirstlane(a.i);
    return a.f;
}

// exp2-based tanh: tanh(x) = 1 - 2/(1 + 2^(2*log2e*x)). ~1e-6 accurate,
// saturates correctly at +-1 (exp2->inf -> rcp->0; exp2->0 -> rcp(1)=1).
__device__ __forceinline__ v2f tanh2(v2f x) {
    const float c = 2.8853900817779268f;  // 2*log2(e)
    float ex = __builtin_amdgcn_exp2f(x.x * c);
    float ey = __builtin_amdgcn_exp2f(x.y * c);
    v2f r = {__builtin_amdgcn_rcpf(ex + 1.f), __builtin_amdgcn_rcpf(ey + 1.f)};
    return fma2(splat2(-2.f), r, splat2(1.f));
}

// Setup: pair-transposed weight tables so packed FMAs get contiguous uniform
// float2 loads. W?2[k][t] = (W[2t][k], W[2t+1][k]), pad t=9.y with 0.
extern "C" __global__ void __launch_bounds__(64)
ltc_setup(const float* __restrict__ Wi, const float* __restrict__ bi,
          const float* __restrict__ Wr, const float* __restrict__ Wo,
          const float* __restrict__ bo,
          float2* __restrict__ Wi2, float2* __restrict__ bi2,
          float2* __restrict__ Wr2, float2* __restrict__ Wo2,
          float2* __restrict__ bo2)
{
    for (int i = threadIdx.x; i < NH * NP; i += 64) {
        int k = i / NP, t = i % NP;
        float rx = Wr[(2 * t) * NH + k];
        float ry = (2 * t + 1 < NH) ? Wr[(2 * t + 1) * NH + k] : 0.f;
        Wr2[i] = make_float2(rx, ry);
        float ox = Wo[(2 * t) * NH + k];
        float oy = (2 * t + 1 < NH) ? Wo[(2 * t + 1) * NH + k] : 0.f;
        Wo2[i] = make_float2(ox, oy);
    }
    // Wi2[col*NP + t] = (Wi[2t][col], Wi[2t+1][col]), col = 0..63
    for (int i = threadIdx.x; i < ND * NP; i += 64) {
        int col = i / NP, t = i % NP;
        float ax = Wi[(2 * t) * ND + col];
        float ay = (2 * t + 1 < NH) ? Wi[(2 * t + 1) * ND + col] : 0.f;
        Wi2[i] = make_float2(ax, ay);
    }
    if (threadIdx.x < NP) {
        int t = threadIdx.x;
        bo2[t] = make_float2(bo[2 * t], (2 * t + 1 < NH) ? bo[2 * t + 1] : 0.f);
        bi2[t] = make_float2(bi[2 * t], (2 * t + 1 < NH) ? bi[2 * t + 1] : 0.f);
    }
}

// Kernel 1: pure |x| reduction (also warms L3 with x). 134 MB read.
extern "C" __global__ void __launch_bounds__(256)
ltc_absum(const float* __restrict__ x, float* __restrict__ partials)
{
    __shared__ float red[4];
    const int t = threadIdx.x;
    const float4* xg = (const float4*)x + (size_t)blockIdx.x * 4096;
    float s = 0.f;
#pragma unroll
    for (int i = 0; i < 16; ++i) {
        const float4 v = xg[i * 256 + t];
        s += fabsf(v.x) + fabsf(v.y) + fabsf(v.z) + fabsf(v.w);
    }
#pragma unroll
    for (int off = 32; off > 0; off >>= 1) s += __shfl_down(s, off, 64);
    if ((t & 63) == 0) red[t >> 6] = s;
    __syncthreads();
    if (t == 0) partials[blockIdx.x] = red[0] + red[1] + red[2] + red[3];
}

// Kernel 2: fused matvec + recurrence + output, TWO ROWS PER THREAD.
// Model from r1/r3/r5: per-SIMD issue density ~33% -- waves stall on the
// 1900 uniform global weight loads in the steps loop; occupancy (3-4
// waves/SIMD) can't cover. Moving the loads (LDS r5, reg-dbuf r4) broke
// codegen. Instead AMORTIZE: thread handles rows l and l+256, so each
// weight load feeds two pk-FMAs (total weight-load instrs halve).
// waves_per_eu(1,3) -> 170-reg budget for the ~160-reg state (r3-validated
// lever). Weights stay plain global loads (r1's tame codegen).
extern "C" __global__ void
__launch_bounds__(256)
__attribute__((amdgpu_waves_per_eu(1, 3)))
ltc_fused(const float* __restrict__ x, const float* __restrict__ partials,
          const v2f* __restrict__ Wi2, const v2f* __restrict__ bi2,
          const v2f* __restrict__ Wr2, const v2f* __restrict__ Wo2,
          const v2f* __restrict__ bo2, const float* __restrict__ tau,
          const float* __restrict__ ta, const int* __restrict__ steps_p,
          float* __restrict__ out)
{
    __shared__ float lds[4 * 64 * 34];  // per-wave tiles; reused for staging
    __shared__ float red[4];
    const int t = threadIdx.x;
    const int l = t & 63, w = t >> 6;
    const int rowbase = blockIdx.x * 512;

    // --- urgency: deterministic re-reduction of the 2048 partials ---
    float ps = 0.f;
#pragma unroll
    for (int i = 0; i < NBLK_ABS / 256; ++i) ps += partials[t + 256 * i];
#pragma unroll
    for (int off = 32; off > 0; off >>= 1) ps += __shfl_down(ps, off, 64);
    if ((t & 63) == 0) red[t >> 6] = ps;
    __syncthreads();
    const float total = red[0] + red[1] + red[2] + red[3];
    const float u = rfl(fmaxf(total * (1.f / ((float)NB * (float)ND)), 0.01f));
    const float inv_u = 1.f / u;

    // --- phase B twice: m2{a,b} = x @ Wi^T + bi for rows t and t+256 ---
    v2f m2a[NP], m2b[NP];
#pragma unroll
    for (int j = 0; j < NP; ++j) { m2a[j] = bi2[j]; m2b[j] = bi2[j]; }
    {
        float* tw = lds + w * (64 * 34);
#pragma unroll 1
        for (int pass = 0; pass < 2; ++pass) {
            v2f* m2 = pass ? m2b : m2a;
            const float4* xg = (const float4*)x +
                               (size_t)(rowbase + pass * 256 + w * 64) * 16;
#pragma unroll
            for (int c = 0; c < 2; ++c) {
#pragma unroll
                for (int i = 0; i < 8; ++i) {
                    const int flat = i * 64 + l, row = flat >> 3, cq = flat & 7;
                    const float4 v = xg[row * 16 + c * 8 + cq];
                    *(float2*)&tw[row * 34 + cq * 4]     = make_float2(v.x, v.y);
                    *(float2*)&tw[row * 34 + cq * 4 + 2] = make_float2(v.z, v.w);
                }
                __syncthreads();  // tile write -> read ordering
#pragma unroll
                for (int q = 0; q < 16; ++q) {
                    const float2 v = *(const float2*)&tw[l * 34 + 2 * q];
                    const int col = c * 32 + 2 * q;
                    const v2f vx = splat2(v.x), vy = splat2(v.y);
                    const v2f* wc0 = Wi2 + (size_t)col * NP;
                    const v2f* wc1 = Wi2 + (size_t)(col + 1) * NP;
#pragma unroll
                    for (int j = 0; j < NP; ++j) m2[j] = fma2(vx, wc0[j], m2[j]);
#pragma unroll
                    for (int j = 0; j < NP; ++j) m2[j] = fma2(vy, wc1[j], m2[j]);
                }
                __syncthreads();  // reads done before next chunk overwrites
            }
        }
    }

    // --- rr2 (wave-uniform) ---
    v2f rr2[NP];
#pragma unroll
    for (int j = 0; j < NP; ++j) {
        int j0 = 2 * j, j1 = (2 * j + 1 < NH) ? 2 * j + 1 : 2 * j;
        float t0 = fminf(10.f, fmaxf(0.01f, tau[j0] * (1.f - ta[j0]) + ta[j0] * inv_u));
        float t1 = fminf(10.f, fmaxf(0.01f, tau[j1] * (1.f - ta[j1]) + ta[j1] * inv_u));
        rr2[j] = (v2f){0.01f / t0, 0.01f / t1};
    }

    v2f h2a[NP], h2b[NP];
#pragma unroll
    for (int j = 0; j < NP; ++j) { h2a[j] = splat2(0.f); h2b[j] = splat2(0.f); }

    // --- recurrence: each weight load feeds BOTH rows' FMAs ---
    const int steps = *steps_p;
    const v2f* wr = Wr2;
#pragma unroll 1
    for (int s = 0; s < steps; ++s) {
        v2f p2a[NP], p2b[NP];
        {
            const v2f ha = splat2(h2a[0].x), hb = splat2(h2b[0].x);
#pragma unroll
            for (int j = 0; j < NP; ++j) {
                const v2f wv = wr[j];
                p2a[j] = fma2(ha, wv, m2a[j]);
                p2b[j] = fma2(hb, wv, m2b[j]);
            }
        }
#pragma unroll
        for (int k = 1; k < NH; ++k) {
            const float hka = (k & 1) ? h2a[k >> 1].y : h2a[k >> 1].x;
            const float hkb = (k & 1) ? h2b[k >> 1].y : h2b[k >> 1].x;
            const v2f ha = splat2(hka), hb = splat2(hkb);
            const v2f* wrow = wr + k * NP;
#pragma unroll
            for (int j = 0; j < NP; ++j) {
                const v2f wv = wrow[j];
                p2a[j] = fma2(ha, wv, p2a[j]);
                p2b[j] = fma2(hb, wv, p2b[j]);
            }
        }
#pragma unroll
        for (int j = 0; j < NP; ++j) p2a[j] = tanh2(p2a[j]);
#pragma unroll
        for (int j = 0; j < NP; ++j) p2b[j] = tanh2(p2b[j]);
#pragma unroll
        for (int j = 0; j < NP; ++j) {
            h2a[j] = fma2(rr2[j], p2a[j] - h2a[j], h2a[j]);
            h2b[j] = fma2(rr2[j], p2b[j] - h2b[j], h2b[j]);
        }
    }

    // --- epilogue: o = h @ Wo^T + bo, shared Wo loads ---
    const v2f* wo = Wo2;
    v2f o2a[NP], o2b[NP];
    {
        const v2f ha = splat2(h2a[0].x), hb = splat2(h2b[0].x);
#pragma unroll
        for (int j = 0; j < NP; ++j) {
            const v2f wv = wo[j], bb = bo2[j];
            o2a[j] = fma2(ha, wv, bb);
            o2b[j] = fma2(hb, wv, bb);
        }
    }
#pragma unroll
    for (int k = 1; k < NH; ++k) {
        const float hka = (k & 1) ? h2a[k >> 1].y : h2a[k >> 1].x;
        const float hkb = (k & 1) ? h2b[k >> 1].y : h2b[k >> 1].x;
        const v2f ha = splat2(hka), hb = splat2(hkb);
        const v2f* worow = wo + k * NP;
#pragma unroll
        for (int j = 0; j < NP; ++j) {
            const v2f wv = worow[j];
            o2a[j] = fma2(ha, wv, o2a[j]);
            o2b[j] = fma2(hb, wv, o2b[j]);
        }
    }

    // --- staged coalesced stores: 4 rounds of 256 rows x 19 ---
    float* st = lds;  // reuse tile LDS: [256][19] staging (19456 B)
    __syncthreads();  // tile's last reads are done
#define STAGE_STORE(arr, dstp)                                              \
    do {                                                                    \
        _Pragma("unroll")                                                   \
        for (int j = 0; j < NH; ++j)                                        \
            st[t * NH + j] = (j & 1) ? arr[j >> 1].y : arr[j >> 1].x;       \
        __syncthreads();                                                    \
        const float4* s4 = (const float4*)st;                               \
        float4* o4 = (float4*)(dstp);                                       \
        _Pragma("unroll")                                                   \
        for (int i = 0; i < 4; ++i) o4[t + i * 256] = s4[t + i * 256];      \
        if (t + 1024 < 1216) o4[t + 1024] = s4[t + 1024];                   \
        __syncthreads();                                                    \
    } while (0)

    STAGE_STORE(o2a, out + (size_t)blockIdx.x * 512 * NH);
    STAGE_STORE(o2b, out + (size_t)blockIdx.x * 512 * NH + 256 * NH);
    STAGE_STORE(h2a, out + (size_t)NB * NH + (size_t)blockIdx.x * 512 * NH);
    STAGE_STORE(h2b, out + (size_t)NB * NH + (size_t)blockIdx.x * 512 * NH + 256 * NH);
#undef STAGE_STORE
}

extern "C" void kernel_launch(void* const* d_in, const int* in_sizes, int n_in,
                              void* d_out, int out_size, void* d_ws, size_t ws_size,
                              hipStream_t stream)
{
    const float* x   = (const float*)d_in[0];
    const float* Wi  = (const float*)d_in[1];
    const float* bi  = (const float*)d_in[2];
    const float* Wr  = (const float*)d_in[3];
    const float* Wo  = (const float*)d_in[4];
    const float* bo  = (const float*)d_in[5];
    const float* tau = (const float*)d_in[6];
    const float* ta  = (const float*)d_in[7];
    const int* steps = (const int*)d_in[8];
    float* out = (float*)d_out;

    // ws layout (all fully overwritten every call)
    float*  partials = (float*)d_ws;                    // 8192 B
    float2* Wr2 = (float2*)((char*)d_ws + 8192);        // 1520 B
    float2* Wo2 = (float2*)((char*)d_ws + 9728);        // 1520 B
    float2* bo2 = (float2*)((char*)d_ws + 11264);       // 80 B
    float2* bi2 = (float2*)((char*)d_ws + 11360);       // 80 B
    float2* Wi2 = (float2*)((char*)d_ws + 11456);       // 5120 B

    ltc_setup<<<1, 64, 0, stream>>>(Wi, bi, Wr, Wo, bo, Wi2, bi2, Wr2, Wo2, bo2);
    ltc_absum<<<NBLK_ABS, 256, 0, stream>>>(x, partials);
    ltc_fused<<<NBLK_F, 256, 0, stream>>>(x, partials, (const v2f*)Wi2,
                                          (const v2f*)bi2, (const v2f*)Wr2,
                                          (const v2f*)Wo2, (const v2f*)bo2,
                                          tau, ta, steps, out);
}